// Round 1
// 363.988 us; speedup vs baseline: 1.0149x; 1.0149x over previous
//
#include <hip/hip_runtime.h>

// GIN (2x GINE conv): bucketed CSR build + scalarized CSR gather + bf16 MFMA
// GEMMs (middle two fused through LDS).
// Pipeline:  K1 wprep (weights->bf16^T, bcnt zero, ptr[N]=E)
//            K2 bin   (4096-edge LDS tile sort -> per-bucket chunks)
//            K3 csr || gemm1  (grid-fused: 196 csr blocks + 782 gemm tiles;
//                              csr and gemm1 are independent until gather)
//            K4 gather(A) -> B          (scalarized csr stream, nt stores)
//            K5 fused_mid: relu(B@W12+cnt*b12)@W21+b21 -> A2
//            K6 gather(A2) -> B2
//            K7 B2 @ W22 + cnt*b22 -> out (f32)
// gather: one wave per node; csr entries are wave-uniform -> readfirstlane
// forces SALU unpack + SGPR-base addressing; VALU does only fma/max/add.

typedef unsigned int uint;
typedef __attribute__((ext_vector_type(8))) short bf16x8;
typedef __attribute__((ext_vector_type(4))) float f32x4;

#define BSHIFT 9             // 512 nodes per bucket -> 196 buckets (2x csr parallelism)
#define BNODES (1 << BSHIFT)

static __device__ __forceinline__ unsigned short f2bf(float f) {
    uint u = __float_as_uint(f);
    uint r = (u + 0x7fffu + ((u >> 16) & 1u)) >> 16;
    return (unsigned short)r;
}

// ---------------- weight prep (+init): W[K][128] fp32 -> Wt[128][K] bf16 ----------------

__global__ void wprep_all(const float* __restrict__ W11, const float* __restrict__ W12,
                          const float* __restrict__ W21, const float* __restrict__ W22,
                          unsigned short* Wt11, unsigned short* Wt12,
                          unsigned short* Wt21, unsigned short* Wt22,
                          int* bcnt, int* ptr, int N, int E) {
    int idx = blockIdx.x * 256 + threadIdx.x;
    if (idx < 256) bcnt[idx] = 0;
    if (idx == 0) ptr[N] = E;
    const float* W; unsigned short* Wt; int K; int off;
    if (idx < 64 * 128)        { W = W11; Wt = Wt11; K = 64;  off = idx; }
    else if (idx < 192 * 128)  { W = W12; Wt = Wt12; K = 128; off = idx - 64 * 128; }
    else if (idx < 320 * 128)  { W = W21; Wt = Wt21; K = 128; off = idx - 192 * 128; }
    else if (idx < 448 * 128)  { W = W22; Wt = Wt22; K = 128; off = idx - 320 * 128; }
    else return;
    int k = off >> 7, n = off & 127;
    Wt[n * K + k] = f2bf(W[k * 128 + n]);
}

// ---------------- binning: 4096-edge tile sort in LDS, coalesced chunk appends ----------------
// entry.x = src | (dloc << 17)  (src < 2^17, dloc < 2^9), entry.y = ea bf16x2

__global__ __launch_bounds__(512) void bin_kernel(
    const int* __restrict__ src, const int* __restrict__ dst,
    const float* __restrict__ ea, int* __restrict__ bcnt,
    int2* __restrict__ barr, int CAP, int E, int B) {
    __shared__ int hist[256];
    __shared__ int bbase[256];
    __shared__ int gbase[256];
    __shared__ int wtot[4];
    __shared__ int2 sorted[4096];
    __shared__ unsigned char bof[4096];
    const int tileBase = blockIdx.x * 4096;
    int n = E - tileBase; if (n > 4096) n = 4096; if (n <= 0) return;
    const int tid = threadIdx.x;
    const int lane = tid & 63;
    if (tid < 256) hist[tid] = 0;
    __syncthreads();

    int2 ent[8]; int bk[8]; int rk[8];
#pragma unroll
    for (int kk = 0; kk < 8; kk++) {
        int i = kk * 512 + tid;
        bk[kk] = -1;
        if (i < n) {
            int e = tileBase + i;
            int s = src[e], d = dst[e];
            float2 a = reinterpret_cast<const float2*>(ea)[e];
            int b = d >> BSHIFT;
            int dloc = d & (BNODES - 1);
            ent[kk].x = s | (dloc << 17);
            ent[kk].y = (int)((uint)f2bf(a.x) | ((uint)f2bf(a.y) << 16));
            bk[kk] = b;
            rk[kk] = atomicAdd(&hist[b], 1);
        }
    }
    __syncthreads();
    // parallel exclusive scan of hist[0..255] -> bbase (shuffle scan, 2 barriers)
    int hv = (tid < 256) ? hist[tid] : 0;
    int inc = hv;
#pragma unroll
    for (int off = 1; off < 64; off <<= 1) {
        int tt = __shfl_up(inc, off, 64);
        if (lane >= off) inc += tt;
    }
    if ((tid >> 6) < 4 && lane == 63) wtot[tid >> 6] = inc;
    __syncthreads();
    if (tid == 0) { int run = 0; for (int i = 0; i < 4; i++) { int tt = wtot[i]; wtot[i] = run; run += tt; } }
    __syncthreads();
    if (tid < 256) bbase[tid] = inc - hv + wtot[tid >> 6];
    if (tid < B && hist[tid] > 0) gbase[tid] = atomicAdd(&bcnt[tid], hist[tid]);
    __syncthreads();
#pragma unroll
    for (int kk = 0; kk < 8; kk++) {
        if (bk[kk] >= 0) {
            int p = bbase[bk[kk]] + rk[kk];
            sorted[p] = ent[kk];
            bof[p] = (unsigned char)bk[kk];
        }
    }
    __syncthreads();
    for (int i = tid; i < n; i += 512) {
        int b = bof[i];
        barr[(long)b * CAP + gbase[b] + (i - bbase[b])] = sorted[i];
    }
}

// ---------------- per-bucket exact CSR (device body; 512-node bucket, 512 threads) ----------------

static __device__ void csr_body(const int2* __restrict__ barr, const int* __restrict__ bcnt,
                                int CAP, int N, int2* __restrict__ csr, int* __restrict__ ptr) {
    __shared__ int hist[BNODES];
    __shared__ int lptr[BNODES];
    __shared__ int wtot[8];
    __shared__ int sbase;
    const int g = blockIdx.x;
    const int tid = threadIdx.x;
    const int lane = tid & 63;
    const int cnt = bcnt[g];
    if (tid == 0) sbase = 0;
    hist[tid] = 0;
    __syncthreads();
    // bucket base = sum of preceding bucket counts (parallel, not a serial chain)
    if (tid < g) atomicAdd(&sbase, bcnt[tid]);
    const int2* my = barr + (long)g * CAP;
    for (int i = tid; i < cnt; i += 512)
        atomicAdd(&hist[((uint)my[i].x) >> 17], 1);
    __syncthreads();
    // exclusive scan of hist via wave shuffle scan (2 barriers instead of 20)
    int v = hist[tid];
    int inc = v;
#pragma unroll
    for (int off = 1; off < 64; off <<= 1) {
        int tt = __shfl_up(inc, off, 64);
        if (lane >= off) inc += tt;
    }
    if (lane == 63) wtot[tid >> 6] = inc;
    __syncthreads();
    if (tid == 0) { int run = 0; for (int i = 0; i < 8; i++) { int tt = wtot[i]; wtot[i] = run; run += tt; } }
    __syncthreads();
    const int base = sbase;
    int excl = inc - v + wtot[tid >> 6];
    lptr[tid] = excl;
    int gnode = g * BNODES + tid;
    if (gnode < N) ptr[gnode] = base + excl;
    __syncthreads();
    for (int i = tid; i < cnt; i += 512) {
        int2 e = my[i];
        int pos = base + atomicAdd(&lptr[((uint)e.x) >> 17], 1);
        int2 o; o.x = e.x & 0x1FFFF; o.y = e.y;
        csr[pos] = o;
    }
}

// ---------------- MFMA GEMM body: C[rowBase..+64][128] = A @ W[K][128] + bias ----------------

template <int K, bool IN_F32, bool OUT_BF16, bool USE_CNT, bool RELU>
static __device__ __forceinline__ void gemm_body(
    const void* __restrict__ Ain, const unsigned short* __restrict__ Wt,
    const float* __restrict__ bias, const int* __restrict__ ptr,
    void* __restrict__ Cout, int N, int tid, long rowBase) {
    constexpr int KS = K / 32;
    const int wave = tid >> 6;
    const int lane = tid & 63;
    const int m = lane & 15, quad = lane >> 4;

    bf16x8 bfrag[2][KS];
#pragma unroll
    for (int ct = 0; ct < 2; ct++) {
        int col = (wave * 2 + ct) * 16 + m;
#pragma unroll
        for (int ks = 0; ks < KS; ks++)
            bfrag[ct][ks] = *(const bf16x8*)(Wt + (long)col * K + ks * 32 + quad * 8);
    }

#pragma unroll
    for (int rt = 0; rt < 4; rt++) {
        long row = rowBase + rt * 16 + m;
        long rc = row < N ? row : (long)N - 1;
        bf16x8 afrag[KS];
        if (IN_F32) {
            const float* arow = (const float*)Ain + rc * K;
#pragma unroll
            for (int ks = 0; ks < KS; ks++) {
                float4 lo = *(const float4*)(arow + ks * 32 + quad * 8);
                float4 hi = *(const float4*)(arow + ks * 32 + quad * 8 + 4);
                bf16x8 f;
                f[0] = (short)f2bf(lo.x); f[1] = (short)f2bf(lo.y);
                f[2] = (short)f2bf(lo.z); f[3] = (short)f2bf(lo.w);
                f[4] = (short)f2bf(hi.x); f[5] = (short)f2bf(hi.y);
                f[6] = (short)f2bf(hi.z); f[7] = (short)f2bf(hi.w);
                afrag[ks] = f;
            }
        } else {
            const unsigned short* arow = (const unsigned short*)Ain + rc * K;
#pragma unroll
            for (int ks = 0; ks < KS; ks++)
                afrag[ks] = *(const bf16x8*)(arow + ks * 32 + quad * 8);
        }

#pragma unroll
        for (int ct = 0; ct < 2; ct++) {
            f32x4 acc = {0.f, 0.f, 0.f, 0.f};
#pragma unroll
            for (int ks = 0; ks < KS; ks++)
                acc = __builtin_amdgcn_mfma_f32_16x16x32_bf16(afrag[ks], bfrag[ct][ks], acc, 0, 0, 0);

            int col = (wave * 2 + ct) * 16 + m;
            float b = bias[col];
#pragma unroll
            for (int r = 0; r < 4; r++) {
                long orow = rowBase + rt * 16 + quad * 4 + r;
                if (orow < N) {
                    float v = acc[r];
                    if (USE_CNT) v += b * (float)(ptr[orow + 1] - ptr[orow] + 1);
                    else v += b;
                    if (RELU) v = fmaxf(v, 0.f);
                    if (OUT_BF16) ((unsigned short*)Cout)[orow * 128 + col] = f2bf(v);
                    else ((float*)Cout)[orow * 128 + col] = v;
                }
            }
        }
    }
}

template <int K, bool IN_F32, bool OUT_BF16, bool USE_CNT, bool RELU>
__global__ __launch_bounds__(256) void gemm_mfma(
    const void* __restrict__ Ain, const unsigned short* __restrict__ Wt,
    const float* __restrict__ bias, const int* __restrict__ ptr,
    void* __restrict__ Cout, int N) {
    gemm_body<K, IN_F32, OUT_BF16, USE_CNT, RELU>(Ain, Wt, bias, ptr, Cout, N,
                                                  threadIdx.x, (long)blockIdx.x * 64);
}

// ---------------- grid-fused: bucket CSR (first CSRB blocks) || layer-1 GEMM ----------------
// csr build and gemm1 have no data dependence; fusing backfills the CUs the
// 196 csr blocks leave idle.

__global__ __launch_bounds__(512) void csr_gemm1(
    const int2* __restrict__ barr, const int* __restrict__ bcnt, int CAP, int N,
    int2* __restrict__ csr, int* __restrict__ ptr, int CSRB,
    const float* __restrict__ x, const unsigned short* __restrict__ Wt11,
    const float* __restrict__ b11, unsigned short* __restrict__ A_bf) {
    if ((int)blockIdx.x < CSRB) {
        csr_body(barr, bcnt, CAP, N, csr, ptr);
    } else {
        int bid = blockIdx.x - CSRB;
        int sub = threadIdx.x >> 8;  // two 64-row tiles per 512-thread block
        gemm_body<64, true, true, false, false>(x, Wt11, b11, nullptr, A_bf, N,
                                                threadIdx.x & 255,
                                                (long)bid * 128 + sub * 64);
    }
}

// ---------------- CSR gather: wave/node, scalarized edge stream ----------------

__global__ __launch_bounds__(256) void gather_kernel(
    const uint* __restrict__ Au, const int* __restrict__ ptr,
    const int2* __restrict__ csr, const float* __restrict__ we,
    uint* __restrict__ Bout, int N) {
    int node = blockIdx.x * 4 + (threadIdx.x >> 6);
    if (node >= N) return;
    node = __builtin_amdgcn_readfirstlane(node);
    const int t = threadIdx.x & 63;
    const int c = 2 * t;
    const float w0x = we[c], w0y = we[c + 1];
    const float w1x = we[128 + c], w1y = we[128 + c + 1];

    const char* Ab = (const char*)Au;
    const uint t4 = (uint)t * 4u;
#define LD(sidx) (*(const uint*)(Ab + ((((uint)(sidx)) << 8) + t4)))
// ev is wave-uniform (SGPR after readfirstlane) -> unpack on SALU; per-lane
// VALU is only 4 fma + 2 max + 2 add + 2 rv-unpack per edge.
#define ACC(rv, ev)                                                      \
    {                                                                    \
        float a0 = __uint_as_float(((uint)(ev)) << 16);                  \
        float a1 = __uint_as_float(((uint)(ev)) & 0xffff0000u);          \
        float vx = __uint_as_float((rv) << 16);                          \
        float vy = __uint_as_float((rv) & 0xffff0000u);                  \
        vx = fmaf(a0, w0x, fmaf(a1, w1x, vx));                           \
        vy = fmaf(a0, w0y, fmaf(a1, w1y, vy));                           \
        ax += fmaxf(vx, 0.f);                                            \
        ay += fmaxf(vy, 0.f);                                            \
    }
#define EDGE(i, off)                                                     \
    int2 c##i = csr[k + (off)];                                          \
    uint s##i = (uint)__builtin_amdgcn_readfirstlane(c##i.x);            \
    uint e##i = (uint)__builtin_amdgcn_readfirstlane(c##i.y);

    uint selfv = LD((uint)node);
    float ax = fmaxf(__uint_as_float(selfv << 16) + w0x + w1x, 0.f);
    float ay = fmaxf(__uint_as_float(selfv & 0xffff0000u) + w0y + w1y, 0.f);

    // wave-uniform edge range -> scalar loop control + scalar csr loads
    int k   = __builtin_amdgcn_readfirstlane(ptr[node]);
    int end = __builtin_amdgcn_readfirstlane(ptr[node + 1]);

    for (; k + 8 <= end; k += 8) {
        EDGE(0, 0) EDGE(1, 1) EDGE(2, 2) EDGE(3, 3)
        EDGE(4, 4) EDGE(5, 5) EDGE(6, 6) EDGE(7, 7)
        uint r0 = LD(s0); uint r1 = LD(s1); uint r2 = LD(s2); uint r3 = LD(s3);
        uint r4 = LD(s4); uint r5 = LD(s5); uint r6 = LD(s6); uint r7 = LD(s7);
        ACC(r0, e0) ACC(r1, e1) ACC(r2, e2) ACC(r3, e3)
        ACC(r4, e4) ACC(r5, e5) ACC(r6, e6) ACC(r7, e7)
    }
    for (; k + 4 <= end; k += 4) {
        EDGE(0, 0) EDGE(1, 1) EDGE(2, 2) EDGE(3, 3)
        uint r0 = LD(s0); uint r1 = LD(s1); uint r2 = LD(s2); uint r3 = LD(s3);
        ACC(r0, e0) ACC(r1, e1) ACC(r2, e2) ACC(r3, e3)
    }
    for (; k < end; k++) {
        EDGE(0, 0)
        uint r0 = LD(s0);
        ACC(r0, e0)
    }
#undef EDGE
#undef ACC
#undef LD
    uint outv = (uint)f2bf(ax) | ((uint)f2bf(ay) << 16);
    // nt store: B is streamed; don't evict A's L2 lines (A reuse is the
    // gather bottleneck: FETCH_SIZE ~ E*128B => ~50% L2 hit today)
    __builtin_nontemporal_store(outv, Bout + (long)node * 64 + t);
}

// ---------------- fused middle GEMMs: A2 = (relu(B@W12 + cnt*b12)) @ W21 + b21 ----------------

__global__ __launch_bounds__(256) void fused_mid_gemm(
    const unsigned short* __restrict__ Bin, const int* __restrict__ ptr,
    const unsigned short* __restrict__ WtA, const float* __restrict__ biasA,
    const unsigned short* __restrict__ WtB, const float* __restrict__ biasB,
    unsigned short* __restrict__ Cout, int N) {
    __shared__ unsigned short ts[64 * 136];
    const int wave = threadIdx.x >> 6;
    const int lane = threadIdx.x & 63;
    const int m = lane & 15, quad = lane >> 4;
    const long rowBase = (long)blockIdx.x * 64;

    bf16x8 bfrag[2][4];
#pragma unroll
    for (int ct = 0; ct < 2; ct++) {
        int col = (wave * 2 + ct) * 16 + m;
#pragma unroll
        for (int ks = 0; ks < 4; ks++)
            bfrag[ct][ks] = *(const bf16x8*)(WtA + (long)col * 128 + ks * 32 + quad * 8);
    }

    f32x4 acc[4][2];
#pragma unroll
    for (int rt = 0; rt < 4; rt++) {
        long row = rowBase + rt * 16 + m;
        long rc = row < N ? row : (long)N - 1;
        const unsigned short* arow = Bin + rc * 128;
        bf16x8 af[4];
#pragma unroll
        for (int ks = 0; ks < 4; ks++)
            af[ks] = *(const bf16x8*)(arow + ks * 32 + quad * 8);
#pragma unroll
        for (int ct = 0; ct < 2; ct++) {
            f32x4 a = {0.f, 0.f, 0.f, 0.f};
#pragma unroll
            for (int ks = 0; ks < 4; ks++)
                a = __builtin_amdgcn_mfma_f32_16x16x32_bf16(af[ks], bfrag[ct][ks], a, 0, 0, 0);
            acc[rt][ct] = a;
        }
    }

#pragma unroll
    for (int rt = 0; rt < 4; rt++) {
        float cntf[4];
#pragma unroll
        for (int r = 0; r < 4; r++) {
            long grow = rowBase + rt * 16 + quad * 4 + r;
            cntf[r] = (grow < N) ? (float)(ptr[grow + 1] - ptr[grow] + 1) : 1.f;
        }
#pragma unroll
        for (int ct = 0; ct < 2; ct++) {
            int col = (wave * 2 + ct) * 16 + m;
            float b = biasA[col];
#pragma unroll
            for (int r = 0; r < 4; r++) {
                int row = rt * 16 + quad * 4 + r;
                ts[row * 136 + col] = f2bf(fmaxf(acc[rt][ct][r] + b * cntf[r], 0.f));
            }
        }
    }
    __syncthreads();

#pragma unroll
    for (int ct = 0; ct < 2; ct++) {
        int col = (wave * 2 + ct) * 16 + m;
#pragma unroll
        for (int ks = 0; ks < 4; ks++)
            bfrag[ct][ks] = *(const bf16x8*)(WtB + (long)col * 128 + ks * 32 + quad * 8);
    }
#pragma unroll
    for (int rt = 0; rt < 4; rt++) {
        const unsigned short* lr = ts + (rt * 16 + m) * 136;
        bf16x8 af[4];
#pragma unroll
        for (int ks = 0; ks < 4; ks++)
            af[ks] = *(const bf16x8*)(lr + ks * 32 + quad * 8);
#pragma unroll
        for (int ct = 0; ct < 2; ct++) {
            f32x4 a = {0.f, 0.f, 0.f, 0.f};
#pragma unroll
            for (int ks = 0; ks < 4; ks++)
                a = __builtin_amdgcn_mfma_f32_16x16x32_bf16(af[ks], bfrag[ct][ks], a, 0, 0, 0);
            int col = (wave * 2 + ct) * 16 + m;
            float b = biasB[col];
#pragma unroll
            for (int r = 0; r < 4; r++) {
                long grow = rowBase + rt * 16 + quad * 4 + r;
                if (grow < N) Cout[grow * 128 + col] = f2bf(a[r] + b);
            }
        }
    }
}

// ---------------- launch ----------------

extern "C" void kernel_launch(void* const* d_in, const int* in_sizes, int n_in,
                              void* d_out, int out_size, void* d_ws, size_t ws_size,
                              hipStream_t stream) {
    const float* x   = (const float*)d_in[0];
    const int*   ei  = (const int*)d_in[1];
    const float* ea  = (const float*)d_in[2];
    const float* W11 = (const float*)d_in[3];
    const float* b11 = (const float*)d_in[4];
    const float* W12 = (const float*)d_in[5];
    const float* b12 = (const float*)d_in[6];
    const float* W21 = (const float*)d_in[7];
    const float* b21 = (const float*)d_in[8];
    const float* W22 = (const float*)d_in[9];
    const float* b22 = (const float*)d_in[10];
    float* out = (float*)d_out;

    const int N = in_sizes[0] / 64;
    const int E = in_sizes[1] / 2;
    const int* src = ei;
    const int* dst = ei + E;

    const int B = (N + BNODES - 1) >> BSHIFT;     // 196 buckets
    const int CAP = E / B + 4096;                 // per-bucket capacity (mean+~45σ slack)

    char* p = (char*)d_ws;
    unsigned short* A_bf = (unsigned short*)p;  p += (size_t)N * 128 * 2;  // 25.6 MB
    unsigned short* B_bf = (unsigned short*)p;
    int2* barr = (int2*)B_bf;                   p += (size_t)N * 128 * 2;  // 25.6 MB (aliased; barr ~19.2 MB)
    int2* csr  = (int2*)p;                      p += (size_t)E * 8;        // 12.8 MB
    int* ptr   = (int*)p;                       p += (size_t)(N + 1) * 4;
    int* bcnt  = (int*)p;                       p += 256 * 4;
    unsigned short* Wt11 = (unsigned short*)p;  p += (size_t)64 * 128 * 2;
    unsigned short* Wt12 = (unsigned short*)p;  p += (size_t)128 * 128 * 2;
    unsigned short* Wt21 = (unsigned short*)p;  p += (size_t)128 * 128 * 2;
    unsigned short* Wt22 = (unsigned short*)p;

    const int binBlocks = (E + 4095) / 4096;      // 391
    const int gatherBlocks = (N + 3) / 4;         // 25000
    const int tileBlocks = (N + 63) / 64;         // 1563
    const int g1Tiles = (N + 127) / 128;          // 782 (128-row tiles, 512 thr)

    wprep_all<<<224, 256, 0, stream>>>(W11, W12, W21, W22,
                                       Wt11, Wt12, Wt21, Wt22,
                                       bcnt, ptr, N, E);
    bin_kernel<<<binBlocks, 512, 0, stream>>>(src, dst, ea, bcnt, barr, CAP, E, B);
    // csr build || layer-1 gemm (independent work, one grid)
    csr_gemm1<<<B + g1Tiles, 512, 0, stream>>>(barr, bcnt, CAP, N, csr, ptr, B,
                                               x, Wt11, b11, A_bf);
    gather_kernel<<<gatherBlocks, 256, 0, stream>>>((const uint*)A_bf, ptr, csr,
                                                    W11 + 64 * 128, (uint*)B_bf, N);
    fused_mid_gemm<<<tileBlocks, 256, 0, stream>>>(B_bf, ptr, Wt12, b12, Wt21, b21, A_bf, N);
    gather_kernel<<<gatherBlocks, 256, 0, stream>>>((const uint*)A_bf, ptr, csr,
                                                    W21 + 128 * 128, (uint*)B_bf, N);
    gemm_mfma<128, false, false, true, false><<<tileBlocks, 256, 0, stream>>>(
        B_bf, Wt22, b22, ptr, out, N);
}

// Round 2
// 347.259 us; speedup vs baseline: 1.0638x; 1.0482x over previous
//
#include <hip/hip_runtime.h>

// GIN (2x GINE conv): bucketed CSR build + scalarized CSR gather fused into
// the following MFMA GEMMs through LDS.
// Pipeline:  K1 wprep (weights->bf16^T, bcnt zero, ptr[N]=E)
//            K2 bin   (4096-edge LDS tile sort -> per-bucket chunks)
//            K3 csr || gemm1  (grid-fused: 196 csr blocks + 782 gemm tiles)
//            K4 gather_mid: gather(A)->LDS; relu(ts@W12+cnt*b12)@W21+b21 -> A2
//            K5 gather_out: gather(A2)->LDS; ts@W22 + cnt*b22 -> out (f32)
// B/B2 are never materialized to HBM (saves ~100MB round-trip + 2 launches).
// gather: one wave per 16 nodes; csr entries wave-uniform -> readfirstlane.

typedef unsigned int uint;
typedef __attribute__((ext_vector_type(8))) short bf16x8;
typedef __attribute__((ext_vector_type(4))) float f32x4;

#define BSHIFT 9             // 512 nodes per bucket -> 196 buckets
#define BNODES (1 << BSHIFT)

static __device__ __forceinline__ unsigned short f2bf(float f) {
    uint u = __float_as_uint(f);
    uint r = (u + 0x7fffu + ((u >> 16) & 1u)) >> 16;
    return (unsigned short)r;
}

// ---------------- weight prep (+init): W[K][128] fp32 -> Wt[128][K] bf16 ----------------

__global__ void wprep_all(const float* __restrict__ W11, const float* __restrict__ W12,
                          const float* __restrict__ W21, const float* __restrict__ W22,
                          unsigned short* Wt11, unsigned short* Wt12,
                          unsigned short* Wt21, unsigned short* Wt22,
                          int* bcnt, int* ptr, int N, int E) {
    int idx = blockIdx.x * 256 + threadIdx.x;
    if (idx < 256) bcnt[idx] = 0;
    if (idx == 0) ptr[N] = E;
    const float* W; unsigned short* Wt; int K; int off;
    if (idx < 64 * 128)        { W = W11; Wt = Wt11; K = 64;  off = idx; }
    else if (idx < 192 * 128)  { W = W12; Wt = Wt12; K = 128; off = idx - 64 * 128; }
    else if (idx < 320 * 128)  { W = W21; Wt = Wt21; K = 128; off = idx - 192 * 128; }
    else if (idx < 448 * 128)  { W = W22; Wt = Wt22; K = 128; off = idx - 320 * 128; }
    else return;
    int k = off >> 7, n = off & 127;
    Wt[n * K + k] = f2bf(W[k * 128 + n]);
}

// ---------------- binning: 4096-edge tile sort in LDS, coalesced chunk appends ----------------
// entry.x = src | (dloc << 17)  (src < 2^17, dloc < 2^9), entry.y = ea bf16x2

__global__ __launch_bounds__(512) void bin_kernel(
    const int* __restrict__ src, const int* __restrict__ dst,
    const float* __restrict__ ea, int* __restrict__ bcnt,
    int2* __restrict__ barr, int CAP, int E, int B) {
    __shared__ int hist[256];
    __shared__ int bbase[256];
    __shared__ int gbase[256];
    __shared__ int wtot[4];
    __shared__ int2 sorted[4096];
    __shared__ unsigned char bof[4096];
    const int tileBase = blockIdx.x * 4096;
    int n = E - tileBase; if (n > 4096) n = 4096; if (n <= 0) return;
    const int tid = threadIdx.x;
    const int lane = tid & 63;
    if (tid < 256) hist[tid] = 0;
    __syncthreads();

    int2 ent[8]; int bk[8]; int rk[8];
#pragma unroll
    for (int kk = 0; kk < 8; kk++) {
        int i = kk * 512 + tid;
        bk[kk] = -1;
        if (i < n) {
            int e = tileBase + i;
            int s = src[e], d = dst[e];
            float2 a = reinterpret_cast<const float2*>(ea)[e];
            int b = d >> BSHIFT;
            int dloc = d & (BNODES - 1);
            ent[kk].x = s | (dloc << 17);
            ent[kk].y = (int)((uint)f2bf(a.x) | ((uint)f2bf(a.y) << 16));
            bk[kk] = b;
            rk[kk] = atomicAdd(&hist[b], 1);
        }
    }
    __syncthreads();
    // parallel exclusive scan of hist[0..255] -> bbase (shuffle scan, 2 barriers)
    int hv = (tid < 256) ? hist[tid] : 0;
    int inc = hv;
#pragma unroll
    for (int off = 1; off < 64; off <<= 1) {
        int tt = __shfl_up(inc, off, 64);
        if (lane >= off) inc += tt;
    }
    if ((tid >> 6) < 4 && lane == 63) wtot[tid >> 6] = inc;
    __syncthreads();
    if (tid == 0) { int run = 0; for (int i = 0; i < 4; i++) { int tt = wtot[i]; wtot[i] = run; run += tt; } }
    __syncthreads();
    if (tid < 256) bbase[tid] = inc - hv + wtot[tid >> 6];
    if (tid < B && hist[tid] > 0) gbase[tid] = atomicAdd(&bcnt[tid], hist[tid]);
    __syncthreads();
#pragma unroll
    for (int kk = 0; kk < 8; kk++) {
        if (bk[kk] >= 0) {
            int p = bbase[bk[kk]] + rk[kk];
            sorted[p] = ent[kk];
            bof[p] = (unsigned char)bk[kk];
        }
    }
    __syncthreads();
    for (int i = tid; i < n; i += 512) {
        int b = bof[i];
        barr[(long)b * CAP + gbase[b] + (i - bbase[b])] = sorted[i];
    }
}

// ---------------- per-bucket exact CSR (device body; 512-node bucket, 512 threads) ----------------

static __device__ void csr_body(const int2* __restrict__ barr, const int* __restrict__ bcnt,
                                int CAP, int N, int2* __restrict__ csr, int* __restrict__ ptr) {
    __shared__ int hist[BNODES];
    __shared__ int lptr[BNODES];
    __shared__ int wtot[8];
    __shared__ int sbase;
    const int g = blockIdx.x;
    const int tid = threadIdx.x;
    const int lane = tid & 63;
    const int cnt = bcnt[g];
    if (tid == 0) sbase = 0;
    hist[tid] = 0;
    __syncthreads();
    // bucket base = sum of preceding bucket counts (parallel, not a serial chain)
    if (tid < g) atomicAdd(&sbase, bcnt[tid]);
    const int2* my = barr + (long)g * CAP;
    for (int i = tid; i < cnt; i += 512)
        atomicAdd(&hist[((uint)my[i].x) >> 17], 1);
    __syncthreads();
    // exclusive scan of hist via wave shuffle scan (2 barriers instead of 20)
    int v = hist[tid];
    int inc = v;
#pragma unroll
    for (int off = 1; off < 64; off <<= 1) {
        int tt = __shfl_up(inc, off, 64);
        if (lane >= off) inc += tt;
    }
    if (lane == 63) wtot[tid >> 6] = inc;
    __syncthreads();
    if (tid == 0) { int run = 0; for (int i = 0; i < 8; i++) { int tt = wtot[i]; wtot[i] = run; run += tt; } }
    __syncthreads();
    const int base = sbase;
    int excl = inc - v + wtot[tid >> 6];
    lptr[tid] = excl;
    int gnode = g * BNODES + tid;
    if (gnode < N) ptr[gnode] = base + excl;
    __syncthreads();
    for (int i = tid; i < cnt; i += 512) {
        int2 e = my[i];
        int pos = base + atomicAdd(&lptr[((uint)e.x) >> 17], 1);
        int2 o; o.x = e.x & 0x1FFFF; o.y = e.y;
        csr[pos] = o;
    }
}

// ---------------- MFMA GEMM body: C[rowBase..+64][128] = A @ W[K][128] + bias ----------------

template <int K, bool IN_F32, bool OUT_BF16, bool USE_CNT, bool RELU>
static __device__ __forceinline__ void gemm_body(
    const void* __restrict__ Ain, const unsigned short* __restrict__ Wt,
    const float* __restrict__ bias, const int* __restrict__ ptr,
    void* __restrict__ Cout, int N, int tid, long rowBase) {
    constexpr int KS = K / 32;
    const int wave = tid >> 6;
    const int lane = tid & 63;
    const int m = lane & 15, quad = lane >> 4;

    bf16x8 bfrag[2][KS];
#pragma unroll
    for (int ct = 0; ct < 2; ct++) {
        int col = (wave * 2 + ct) * 16 + m;
#pragma unroll
        for (int ks = 0; ks < KS; ks++)
            bfrag[ct][ks] = *(const bf16x8*)(Wt + (long)col * K + ks * 32 + quad * 8);
    }

#pragma unroll
    for (int rt = 0; rt < 4; rt++) {
        long row = rowBase + rt * 16 + m;
        long rc = row < N ? row : (long)N - 1;
        bf16x8 afrag[KS];
        if (IN_F32) {
            const float* arow = (const float*)Ain + rc * K;
#pragma unroll
            for (int ks = 0; ks < KS; ks++) {
                float4 lo = *(const float4*)(arow + ks * 32 + quad * 8);
                float4 hi = *(const float4*)(arow + ks * 32 + quad * 8 + 4);
                bf16x8 f;
                f[0] = (short)f2bf(lo.x); f[1] = (short)f2bf(lo.y);
                f[2] = (short)f2bf(lo.z); f[3] = (short)f2bf(lo.w);
                f[4] = (short)f2bf(hi.x); f[5] = (short)f2bf(hi.y);
                f[6] = (short)f2bf(hi.z); f[7] = (short)f2bf(hi.w);
                afrag[ks] = f;
            }
        } else {
            const unsigned short* arow = (const unsigned short*)Ain + rc * K;
#pragma unroll
            for (int ks = 0; ks < KS; ks++)
                afrag[ks] = *(const bf16x8*)(arow + ks * 32 + quad * 8);
        }

#pragma unroll
        for (int ct = 0; ct < 2; ct++) {
            f32x4 acc = {0.f, 0.f, 0.f, 0.f};
#pragma unroll
            for (int ks = 0; ks < KS; ks++)
                acc = __builtin_amdgcn_mfma_f32_16x16x32_bf16(afrag[ks], bfrag[ct][ks], acc, 0, 0, 0);

            int col = (wave * 2 + ct) * 16 + m;
            float b = bias[col];
#pragma unroll
            for (int r = 0; r < 4; r++) {
                long orow = rowBase + rt * 16 + quad * 4 + r;
                if (orow < N) {
                    float v = acc[r];
                    if (USE_CNT) v += b * (float)(ptr[orow + 1] - ptr[orow] + 1);
                    else v += b;
                    if (RELU) v = fmaxf(v, 0.f);
                    if (OUT_BF16) ((unsigned short*)Cout)[orow * 128 + col] = f2bf(v);
                    else ((float*)Cout)[orow * 128 + col] = v;
                }
            }
        }
    }
}

// ---------------- grid-fused: bucket CSR (first CSRB blocks) || layer-1 GEMM ----------------

__global__ __launch_bounds__(512) void csr_gemm1(
    const int2* __restrict__ barr, const int* __restrict__ bcnt, int CAP, int N,
    int2* __restrict__ csr, int* __restrict__ ptr, int CSRB,
    const float* __restrict__ x, const unsigned short* __restrict__ Wt11,
    const float* __restrict__ b11, unsigned short* __restrict__ A_bf) {
    if ((int)blockIdx.x < CSRB) {
        csr_body(barr, bcnt, CAP, N, csr, ptr);
    } else {
        int bid = blockIdx.x - CSRB;
        int sub = threadIdx.x >> 8;  // two 64-row tiles per 512-thread block
        gemm_body<64, true, true, false, false>(x, Wt11, b11, nullptr, A_bf, N,
                                                threadIdx.x & 255,
                                                (long)bid * 128 + sub * 64);
    }
}

// ---------------- CSR gather into LDS tile: wave gathers 16 nodes ----------------
// ts layout: [64 rows][136 shorts] (= [64][68] uints), same conflict-free
// layout the MFMA stage reads as A-fragments.

static __device__ __forceinline__ void gather_lds(
    const uint* __restrict__ Au, const int* __restrict__ ptr,
    const int2* __restrict__ csr, const float* __restrict__ we,
    uint* __restrict__ ts_u, int N, int tid, int rowBase) {
    const int w = tid >> 6;
    const int t = tid & 63;
    const int c = 2 * t;
    const float w0x = we[c], w0y = we[c + 1];
    const float w1x = we[128 + c], w1y = we[128 + c + 1];
    const char* Ab = (const char*)Au;
    const uint t4 = (uint)t * 4u;
#define LD(sidx) (*(const uint*)(Ab + ((((uint)(sidx)) << 8) + t4)))
#define ACC(rv, ev)                                                      \
    {                                                                    \
        float a0 = __uint_as_float(((uint)(ev)) << 16);                  \
        float a1 = __uint_as_float(((uint)(ev)) & 0xffff0000u);          \
        float vx = __uint_as_float((rv) << 16);                          \
        float vy = __uint_as_float((rv) & 0xffff0000u);                  \
        vx = fmaf(a0, w0x, fmaf(a1, w1x, vx));                           \
        vy = fmaf(a0, w0y, fmaf(a1, w1y, vy));                           \
        ax += fmaxf(vx, 0.f);                                            \
        ay += fmaxf(vy, 0.f);                                            \
    }
#define EDGE(i, off)                                                     \
    int2 c##i = csr[k + (off)];                                          \
    uint s##i = (uint)__builtin_amdgcn_readfirstlane(c##i.x);            \
    uint e##i = (uint)__builtin_amdgcn_readfirstlane(c##i.y);

    for (int i = 0; i < 16; i++) {
        int node = rowBase + w * 16 + i;
        if (node >= N) break;                 // wave-uniform

        uint selfv = LD((uint)node);
        float ax = fmaxf(__uint_as_float(selfv << 16) + w0x + w1x, 0.f);
        float ay = fmaxf(__uint_as_float(selfv & 0xffff0000u) + w0y + w1y, 0.f);

        int k   = __builtin_amdgcn_readfirstlane(ptr[node]);
        int end = __builtin_amdgcn_readfirstlane(ptr[node + 1]);

        for (; k + 8 <= end; k += 8) {
            EDGE(0, 0) EDGE(1, 1) EDGE(2, 2) EDGE(3, 3)
            EDGE(4, 4) EDGE(5, 5) EDGE(6, 6) EDGE(7, 7)
            uint r0 = LD(s0); uint r1 = LD(s1); uint r2 = LD(s2); uint r3 = LD(s3);
            uint r4 = LD(s4); uint r5 = LD(s5); uint r6 = LD(s6); uint r7 = LD(s7);
            ACC(r0, e0) ACC(r1, e1) ACC(r2, e2) ACC(r3, e3)
            ACC(r4, e4) ACC(r5, e5) ACC(r6, e6) ACC(r7, e7)
        }
        for (; k + 4 <= end; k += 4) {
            EDGE(0, 0) EDGE(1, 1) EDGE(2, 2) EDGE(3, 3)
            uint r0 = LD(s0); uint r1 = LD(s1); uint r2 = LD(s2); uint r3 = LD(s3);
            ACC(r0, e0) ACC(r1, e1) ACC(r2, e2) ACC(r3, e3)
        }
        for (; k < end; k++) {
            EDGE(0, 0)
            uint r0 = LD(s0);
            ACC(r0, e0)
        }
        ts_u[(w * 16 + i) * 68 + t] = (uint)f2bf(ax) | ((uint)f2bf(ay) << 16);
    }
#undef EDGE
#undef ACC
#undef LD
}

// ---------------- fused gather1 + middle GEMMs: A2 = relu(gather(A)@W12+cnt*b12)@W21+b21 ----------------

__global__ __launch_bounds__(256, 4) void gather_mid(
    const uint* __restrict__ Au, const int* __restrict__ ptr,
    const int2* __restrict__ csr, const float* __restrict__ we,
    const unsigned short* __restrict__ WtA, const float* __restrict__ biasA,
    const unsigned short* __restrict__ WtB, const float* __restrict__ biasB,
    unsigned short* __restrict__ Cout, int N) {
    __shared__ uint ts_u[64 * 68];
    unsigned short* ts = (unsigned short*)ts_u;
    const int tid = threadIdx.x;
    const int rowBase = blockIdx.x * 64;

    gather_lds(Au, ptr, csr, we, ts_u, N, tid, rowBase);
    __syncthreads();

    const int wave = tid >> 6, lane = tid & 63;
    const int m = lane & 15, quad = lane >> 4;

    bf16x8 bfrag[2][4];
#pragma unroll
    for (int ct = 0; ct < 2; ct++) {
        int col = (wave * 2 + ct) * 16 + m;
#pragma unroll
        for (int ks = 0; ks < 4; ks++)
            bfrag[ct][ks] = *(const bf16x8*)(WtA + (long)col * 128 + ks * 32 + quad * 8);
    }

    f32x4 acc[4][2];
#pragma unroll
    for (int rt = 0; rt < 4; rt++) {
        const unsigned short* lr = ts + (rt * 16 + m) * 136;
        bf16x8 af[4];
#pragma unroll
        for (int ks = 0; ks < 4; ks++)
            af[ks] = *(const bf16x8*)(lr + ks * 32 + quad * 8);
#pragma unroll
        for (int ct = 0; ct < 2; ct++) {
            f32x4 a = {0.f, 0.f, 0.f, 0.f};
#pragma unroll
            for (int ks = 0; ks < 4; ks++)
                a = __builtin_amdgcn_mfma_f32_16x16x32_bf16(af[ks], bfrag[ct][ks], a, 0, 0, 0);
            acc[rt][ct] = a;
        }
    }
    __syncthreads();   // all ts reads done before overwrite

#pragma unroll
    for (int rt = 0; rt < 4; rt++) {
        float cntf[4];
#pragma unroll
        for (int r = 0; r < 4; r++) {
            long grow = rowBase + rt * 16 + quad * 4 + r;
            cntf[r] = (grow < N) ? (float)(ptr[grow + 1] - ptr[grow] + 1) : 1.f;
        }
#pragma unroll
        for (int ct = 0; ct < 2; ct++) {
            int col = (wave * 2 + ct) * 16 + m;
            float b = biasA[col];
#pragma unroll
            for (int r = 0; r < 4; r++) {
                int row = rt * 16 + quad * 4 + r;
                ts[row * 136 + col] = f2bf(fmaxf(acc[rt][ct][r] + b * cntf[r], 0.f));
            }
        }
    }
    __syncthreads();

#pragma unroll
    for (int ct = 0; ct < 2; ct++) {
        int col = (wave * 2 + ct) * 16 + m;
#pragma unroll
        for (int ks = 0; ks < 4; ks++)
            bfrag[ct][ks] = *(const bf16x8*)(WtB + (long)col * 128 + ks * 32 + quad * 8);
    }
#pragma unroll
    for (int rt = 0; rt < 4; rt++) {
        const unsigned short* lr = ts + (rt * 16 + m) * 136;
        bf16x8 af[4];
#pragma unroll
        for (int ks = 0; ks < 4; ks++)
            af[ks] = *(const bf16x8*)(lr + ks * 32 + quad * 8);
#pragma unroll
        for (int ct = 0; ct < 2; ct++) {
            f32x4 a = {0.f, 0.f, 0.f, 0.f};
#pragma unroll
            for (int ks = 0; ks < 4; ks++)
                a = __builtin_amdgcn_mfma_f32_16x16x32_bf16(af[ks], bfrag[ct][ks], a, 0, 0, 0);
            int col = (wave * 2 + ct) * 16 + m;
            float b = biasB[col];
#pragma unroll
            for (int r = 0; r < 4; r++) {
                long grow = rowBase + rt * 16 + quad * 4 + r;
                if (grow < N) Cout[grow * 128 + col] = f2bf(a[r] + b);
            }
        }
    }
}

// ---------------- fused gather2 + last GEMM: out = gather(A2)@W22 + cnt*b22 (f32) ----------------

__global__ __launch_bounds__(256, 4) void gather_out(
    const uint* __restrict__ Au, const int* __restrict__ ptr,
    const int2* __restrict__ csr, const float* __restrict__ we,
    const unsigned short* __restrict__ Wt, const float* __restrict__ bias,
    float* __restrict__ out, int N) {
    __shared__ uint ts_u[64 * 68];
    unsigned short* ts = (unsigned short*)ts_u;
    const int tid = threadIdx.x;
    const int rowBase = blockIdx.x * 64;

    gather_lds(Au, ptr, csr, we, ts_u, N, tid, rowBase);
    __syncthreads();

    const int wave = tid >> 6, lane = tid & 63;
    const int m = lane & 15, quad = lane >> 4;

    bf16x8 bfrag[2][4];
#pragma unroll
    for (int ct = 0; ct < 2; ct++) {
        int col = (wave * 2 + ct) * 16 + m;
#pragma unroll
        for (int ks = 0; ks < 4; ks++)
            bfrag[ct][ks] = *(const bf16x8*)(Wt + (long)col * 128 + ks * 32 + quad * 8);
    }

#pragma unroll
    for (int rt = 0; rt < 4; rt++) {
        const unsigned short* lr = ts + (rt * 16 + m) * 136;
        bf16x8 af[4];
#pragma unroll
        for (int ks = 0; ks < 4; ks++)
            af[ks] = *(const bf16x8*)(lr + ks * 32 + quad * 8);
#pragma unroll
        for (int ct = 0; ct < 2; ct++) {
            f32x4 a = {0.f, 0.f, 0.f, 0.f};
#pragma unroll
            for (int ks = 0; ks < 4; ks++)
                a = __builtin_amdgcn_mfma_f32_16x16x32_bf16(af[ks], bfrag[ct][ks], a, 0, 0, 0);
            int col = (wave * 2 + ct) * 16 + m;
            float b = bias[col];
#pragma unroll
            for (int r = 0; r < 4; r++) {
                long grow = rowBase + rt * 16 + quad * 4 + r;
                if (grow < N) {
                    float cnt = (float)(ptr[grow + 1] - ptr[grow] + 1);
                    out[grow * 128 + col] = a[r] + b * cnt;
                }
            }
        }
    }
}

// ---------------- launch ----------------

extern "C" void kernel_launch(void* const* d_in, const int* in_sizes, int n_in,
                              void* d_out, int out_size, void* d_ws, size_t ws_size,
                              hipStream_t stream) {
    const float* x   = (const float*)d_in[0];
    const int*   ei  = (const int*)d_in[1];
    const float* ea  = (const float*)d_in[2];
    const float* W11 = (const float*)d_in[3];
    const float* b11 = (const float*)d_in[4];
    const float* W12 = (const float*)d_in[5];
    const float* b12 = (const float*)d_in[6];
    const float* W21 = (const float*)d_in[7];
    const float* b21 = (const float*)d_in[8];
    const float* W22 = (const float*)d_in[9];
    const float* b22 = (const float*)d_in[10];
    float* out = (float*)d_out;

    const int N = in_sizes[0] / 64;
    const int E = in_sizes[1] / 2;
    const int* src = ei;
    const int* dst = ei + E;

    const int B = (N + BNODES - 1) >> BSHIFT;     // 196 buckets
    const int CAP = E / B + 4096;                 // per-bucket capacity

    char* p = (char*)d_ws;
    unsigned short* A_bf = (unsigned short*)p;  p += (size_t)N * 128 * 2;  // 25.6 MB
    unsigned short* A2_bf = (unsigned short*)p;
    int2* barr = (int2*)A2_bf;                  p += (size_t)N * 128 * 2;  // 25.6 MB (aliased; barr consumed before A2 written)
    int2* csr  = (int2*)p;                      p += (size_t)E * 8;        // 12.8 MB
    int* ptr   = (int*)p;                       p += (size_t)(N + 1) * 4;
    int* bcnt  = (int*)p;                       p += 256 * 4;
    unsigned short* Wt11 = (unsigned short*)p;  p += (size_t)64 * 128 * 2;
    unsigned short* Wt12 = (unsigned short*)p;  p += (size_t)128 * 128 * 2;
    unsigned short* Wt21 = (unsigned short*)p;  p += (size_t)128 * 128 * 2;
    unsigned short* Wt22 = (unsigned short*)p;

    const int binBlocks = (E + 4095) / 4096;      // 391
    const int tileBlocks = (N + 63) / 64;         // 1563
    const int g1Tiles = (N + 127) / 128;          // 782 (128-row tiles, 512 thr)

    wprep_all<<<224, 256, 0, stream>>>(W11, W12, W21, W22,
                                       Wt11, Wt12, Wt21, Wt22,
                                       bcnt, ptr, N, E);
    bin_kernel<<<binBlocks, 512, 0, stream>>>(src, dst, ea, bcnt, barr, CAP, E, B);
    // csr build || layer-1 gemm (independent work, one grid)
    csr_gemm1<<<B + g1Tiles, 512, 0, stream>>>(barr, bcnt, CAP, N, csr, ptr, B,
                                               x, Wt11, b11, A_bf);
    // gather(A) + relu-GEMM + GEMM -> A2  (B never hits HBM)
    gather_mid<<<tileBlocks, 256, 0, stream>>>((const uint*)A_bf, ptr, csr,
                                               W11 + 64 * 128, Wt12, b12, Wt21, b21,
                                               A2_bf, N);
    // gather(A2) + GEMM -> out  (B2 never hits HBM)
    gather_out<<<tileBlocks, 256, 0, stream>>>((const uint*)A2_bf, ptr, csr,
                                               W21 + 128 * 128, Wt22, b22, out, N);
}